// Round 5
// baseline (845.736 us; speedup 1.0000x reference)
//
#include <hip/hip_runtime.h>
#include <hip/hip_cooperative_groups.h>
#include <math.h>

namespace cg = cooperative_groups;

#define IN_UNITS 1152
#define OUT_UNITS 32
#define BATCH 64
#define NCHK 48            // i-chunks; 48%8==0 -> chunk c on XCD c%8 (bid%8==c%8)
#define IPB 24             // i's per chunk
#define NG 3               // i-groups per chunk (8 i x 32 o per group)
#define BPB 4              // batches per block
#define NBQ (BATCH/BPB)    // 16
#define NBLK (NCHK*NBQ)    // 768 = 3 blocks/CU
#define PREC 33            // floats per (chunk,o): S, mu[16], v2[16]
#define PBLK (OUT_UNITS*PREC)   // 1056

// ---------------- cooperative single-kernel path ----------------
// 3 x (stats -> grid.sync -> finalize -> grid.sync), W pinned in registers.
// thread layout: t = il*32 + o; lanes l and l^32 share o -> shfl_xor(32).
__global__ __launch_bounds__(256, 3) void caps_all(
    const float* __restrict__ a_in, const float* __restrict__ Mm,
    const float* __restrict__ Wg,
    float* __restrict__ part,
    float* __restrict__ mu_g, float* __restrict__ i2v_g, float* __restrict__ lae_g,
    const float* __restrict__ beta_u, const float* __restrict__ beta_a,
    float* __restrict__ out)
{
    const int t  = threadIdx.x;
    const int o  = t & 31;
    const int il = t >> 5;
    const int wv = t >> 6;
    const int lane = t & 63;
    const int bid = blockIdx.x;
    const int c  = bid % NCHK;
    const int bq = bid / NCHK;
    const int i0 = c * IPB;

    __shared__ float sBuf[4][PBLK];   // 16.9 KB

    // Pin this thread's 3 W rows (i = i0+g*8+il, fixed o) in registers.
    float w[NG][16];
    #pragma unroll
    for (int g = 0; g < NG; ++g) {
        const float4* wp = (const float4*)(Wg + (((i0 + g*8 + il)*32 + o) << 4));
        *(float4*)&w[g][0]  = wp[0];
        *(float4*)&w[g][4]  = wp[1];
        *(float4*)&w[g][8]  = wp[2];
        *(float4*)&w[g][12] = wp[3];
    }

    #pragma unroll
    for (int it = 0; it < 3; ++it) {
        const float lamb = (it == 0) ? 0.01f : (it == 1) ? 0.012f : 0.0144f;

        for (int bb = 0; bb < BPB; ++bb) {
            const int b = bq*BPB + bb;
            float rmu[16], ri2[16], lae = 0.f;
            if (it > 0) {
                #pragma unroll
                for (int k = 0; k < 16; ++k) {
                    rmu[k] = mu_g[b*512 + k*32 + o];
                    ri2[k] = i2v_g[b*512 + k*32 + o];
                }
                lae = lae_g[b*32 + o];
            }

            float pS = 0.f, pmu[16], pv2[16];
            #pragma unroll
            for (int k = 0; k < 16; ++k) { pmu[k] = 0.f; pv2[k] = 0.f; }

            #pragma unroll
            for (int g = 0; g < NG; ++g) {
                const int i = i0 + g*8 + il;
                float Mr[16];   // 64B row broadcast to 32 lanes via L1
                const float4* mp = (const float4*)(Mm + ((b*IN_UNITS + i) << 4));
                *(float4*)&Mr[0]  = mp[0];
                *(float4*)&Mr[4]  = mp[1];
                *(float4*)&Mr[8]  = mp[2];
                *(float4*)&Mr[12] = mp[3];
                const float a_val = a_in[b*IN_UNITS + i];

                float v[16];
                #pragma unroll
                for (int x = 0; x < 4; ++x) {
                    #pragma unroll
                    for (int z = 0; z < 4; ++z) {
                        float acc = 0.f;
                        #pragma unroll
                        for (int y = 0; y < 4; ++y)
                            acc = fmaf(Mr[x*4 + y], w[g][y*4 + z], acc);
                        v[x*4 + z] = acc;
                    }
                }

                float wgt;
                if (it == 0) {
                    wgt = a_val * (1.0f/32.0f);          // R0 = 1/32
                } else {
                    float ex0 = 0.f, ex1 = 0.f;
                    #pragma unroll
                    for (int k = 0; k < 16; k += 2) {
                        float d0 = v[k]   - rmu[k];
                        float d1 = v[k+1] - rmu[k+1];
                        ex0 = fmaf(d0*d0, ri2[k],   ex0);
                        ex1 = fmaf(d1*d1, ri2[k+1], ex1);
                    }
                    float logit = lae - (ex0 + ex1);     // log a + log eff + exponent
                    float mx = logit;
                    #pragma unroll
                    for (int m = 16; m >= 1; m >>= 1) mx = fmaxf(mx, __shfl_xor(mx, m));
                    float e = __expf(logit - mx);
                    float s = e;
                    #pragma unroll
                    for (int m = 16; m >= 1; m >>= 1) s += __shfl_xor(s, m);
                    wgt = (e / s) * a_val;               // R over o, * input_a
                }

                pS += wgt;
                #pragma unroll
                for (int k = 0; k < 16; ++k) {
                    pmu[k] = fmaf(wgt, v[k], pmu[k]);
                    pv2[k] = fmaf(wgt*v[k], v[k], pv2[k]);
                }
            }

            // lanes l <-> l^32 share o
            pS += __shfl_xor(pS, 32);
            #pragma unroll
            for (int k = 0; k < 16; ++k) {
                pmu[k] += __shfl_xor(pmu[k], 32);
                pv2[k] += __shfl_xor(pv2[k], 32);
            }
            __syncthreads();   // sBuf free (prev bb's readers done)
            if (lane < 32) {
                float* r = &sBuf[wv][o*PREC];
                r[0] = pS;
                #pragma unroll
                for (int k = 0; k < 16; ++k) { r[1+k] = pmu[k]; r[17+k] = pv2[k]; }
            }
            __syncthreads();
            float* dst = part + (b*NCHK + c)*PBLK;
            for (int idx = t; idx < PBLK; idx += 256)
                dst[idx] = sBuf[0][idx] + sBuf[1][idx] + sBuf[2][idx] + sBuf[3][idx];
        }

        __threadfence();
        cg::this_grid().sync();

        // finalize: block b (b<64) reduces its 48 chunk-partials
        if (bid < BATCH) {
            const int b = bid;
            const int seg = t >> 5;   // 0..7, 6 chunks each
            float S = 0.f, m[16], q[16];
            #pragma unroll
            for (int k = 0; k < 16; ++k) { m[k] = 0.f; q[k] = 0.f; }
            for (int cc = seg; cc < NCHK; cc += 8) {
                const float* p = part + (b*NCHK + cc)*PBLK + o*PREC;
                S += p[0];
                #pragma unroll
                for (int k = 0; k < 16; ++k) { m[k] += p[1+k]; q[k] += p[17+k]; }
            }
            __syncthreads();   // sBuf free from stats phase
            if (seg >= 4) {
                float* r = &sBuf[seg-4][o*PREC];
                r[0] = S;
                #pragma unroll
                for (int k = 0; k < 16; ++k) { r[1+k] = m[k]; r[17+k] = q[k]; }
            }
            __syncthreads();
            if (seg < 4) {
                float* r = &sBuf[seg][o*PREC];
                r[0] += S;
                #pragma unroll
                for (int k = 0; k < 16; ++k) { r[1+k] += m[k]; r[17+k] += q[k]; }
            }
            __syncthreads();
            if (t < 32) {
                S = 0.f;
                #pragma unroll
                for (int k = 0; k < 16; ++k) { m[k] = 0.f; q[k] = 0.f; }
                #pragma unroll
                for (int s = 0; s < 4; ++s) {
                    const float* r = &sBuf[s][o*PREC];
                    S += r[0];
                    #pragma unroll
                    for (int k = 0; k < 16; ++k) { m[k] += r[1+k]; q[k] += r[17+k]; }
                }
                const float invS = 1.f / S;
                float mu[16], var[16], logvarsum = 0.f;
                #pragma unroll
                for (int k = 0; k < 16; ++k) {
                    mu[k] = m[k] * invS;
                    float vv = q[k]*invS - mu[k]*mu[k];   // E[v^2] - mu^2
                    vv = fmaxf(vv, 1e-30f);
                    var[k] = vv;
                    logvarsum += logf(vv);
                }
                const float cost = S * (16.f*beta_u[o] + 0.5f*logvarsum);
                const float x = lamb * (beta_a[o] - cost);
                const float log_a = (x >= 0.f) ? -log1pf(expf(-x)) : (x - log1pf(expf(x)));
                const float LOG2PI = 1.8378770664093453f;
                const float logeff = 16.f*LOG2PI + logvarsum;

                lae_g[b*32 + o] = log_a + logeff;
                #pragma unroll
                for (int k = 0; k < 16; ++k) {
                    mu_g[b*512 + k*32 + o]  = mu[k];
                    i2v_g[b*512 + k*32 + o] = 0.5f / var[k];
                }
                if (it == 2) {
                    const int tid = b*32 + o;
                    out[tid] = 1.f / (1.f + expf(-x));                      // a
                    #pragma unroll
                    for (int k = 0; k < 16; ++k)
                        out[BATCH*OUT_UNITS + tid*16 + k] = mu[k];          // mu
                }
            }
        }

        if (it < 2) {
            __threadfence();
            cg::this_grid().sync();
        }
    }
}

// ---------------- fallback multi-kernel path (proven, round 3) ----------------
__global__ __launch_bounds__(256) void w_transpose(
    const float* __restrict__ W, float* __restrict__ Wt)
{
    const int gid = blockIdx.x*256 + threadIdx.x;
    const int i = gid >> 9, r = gid & 511, o = r >> 4, ch = r & 15;
    Wt[((i*4 + (ch>>2))*32 + o)*4 + (ch&3)] = W[gid];
}

template<int MODE>
__global__ __launch_bounds__(256, 4) void caps_main(
    const float* __restrict__ a_in, const float* __restrict__ Mm,
    const float4* __restrict__ Wt4,
    const float* __restrict__ mu_g, const float* __restrict__ i2v_g,
    const float* __restrict__ lae_g,
    float* __restrict__ part)
{
    const int t  = threadIdx.x;
    const int o  = t & 31;
    const int il = t >> 5;
    const int wv = t >> 6;
    const int lane = t & 63;
    const int b = blockIdx.y;
    const int c = blockIdx.x;
    const int i0 = c * IPB;

    __shared__ float sMu[MODE ? 512 : 1];
    __shared__ float sI2[MODE ? 512 : 1];
    __shared__ float sLae[MODE ? 32 : 1];
    __shared__ float sRed[2][PBLK];

    if (MODE) {
        for (int idx = t; idx < 512; idx += 256) {
            sMu[idx] = mu_g[b*512 + idx];
            sI2[idx] = i2v_g[b*512 + idx];
        }
        if (t < 32) sLae[t] = lae_g[b*32 + t];
        __syncthreads();
    }

    float pS = 0.f, pmu[16], pv2[16];
    #pragma unroll
    for (int k = 0; k < 16; ++k) { pmu[k] = 0.f; pv2[k] = 0.f; }

    #pragma unroll
    for (int g = 0; g < NG; ++g) {
        const int i = i0 + g*8 + il;
        float w[16];
        #pragma unroll
        for (int y = 0; y < 4; ++y)
            *(float4*)&w[y*4] = Wt4[(i*4 + y)*32 + o];

        float Mr[16];
        const float4* mp = (const float4*)Mm + (b*IN_UNITS + i)*4;
        *(float4*)&Mr[0]  = mp[0];
        *(float4*)&Mr[4]  = mp[1];
        *(float4*)&Mr[8]  = mp[2];
        *(float4*)&Mr[12] = mp[3];
        const float a_val = a_in[b*IN_UNITS + i];

        float v[16];
        #pragma unroll
        for (int x = 0; x < 4; ++x) {
            #pragma unroll
            for (int z = 0; z < 4; ++z) {
                float acc = 0.f;
                #pragma unroll
                for (int y = 0; y < 4; ++y)
                    acc = fmaf(Mr[x*4 + y], w[y*4 + z], acc);
                v[x*4 + z] = acc;
            }
        }

        float wgt;
        if (MODE == 0) {
            wgt = a_val * (1.0f/32.0f);
        } else {
            float ex0 = 0.f, ex1 = 0.f;
            #pragma unroll
            for (int k = 0; k < 16; k += 2) {
                float d0 = v[k]   - sMu[k*32 + o];
                float d1 = v[k+1] - sMu[(k+1)*32 + o];
                ex0 = fmaf(d0*d0, sI2[k*32 + o], ex0);
                ex1 = fmaf(d1*d1, sI2[(k+1)*32 + o], ex1);
            }
            float logit = sLae[o] - (ex0 + ex1);
            float mx = logit;
            #pragma unroll
            for (int m = 16; m >= 1; m >>= 1) mx = fmaxf(mx, __shfl_xor(mx, m));
            float e = __expf(logit - mx);
            float s = e;
            #pragma unroll
            for (int m = 16; m >= 1; m >>= 1) s += __shfl_xor(s, m);
            wgt = (e / s) * a_val;
        }

        pS += wgt;
        #pragma unroll
        for (int k = 0; k < 16; ++k) {
            pmu[k] = fmaf(wgt, v[k], pmu[k]);
            pv2[k] = fmaf(wgt*v[k], v[k], pv2[k]);
        }
    }

    pS += __shfl_xor(pS, 32);
    #pragma unroll
    for (int k = 0; k < 16; ++k) {
        pmu[k] += __shfl_xor(pmu[k], 32);
        pv2[k] += __shfl_xor(pv2[k], 32);
    }
    __syncthreads();
    if (wv >= 2 && lane < 32) {
        float* r = &sRed[wv-2][o*PREC];
        r[0] = pS;
        #pragma unroll
        for (int k = 0; k < 16; ++k) { r[1+k] = pmu[k]; r[17+k] = pv2[k]; }
    }
    __syncthreads();
    if (wv < 2 && lane < 32) {
        float* r = &sRed[wv][o*PREC];
        r[0] += pS;
        #pragma unroll
        for (int k = 0; k < 16; ++k) { r[1+k] += pmu[k]; r[17+k] += pv2[k]; }
    }
    __syncthreads();
    float* dst = part + ((size_t)b*NCHK + c)*PBLK;
    for (int idx = t; idx < PBLK; idx += 256)
        dst[idx] = sRed[0][idx] + sRed[1][idx];
}

__global__ __launch_bounds__(256) void caps_fin(
    const float* __restrict__ part,
    const float* __restrict__ beta_u, const float* __restrict__ beta_a,
    float* __restrict__ mu_g, float* __restrict__ i2v_g, float* __restrict__ lae_g,
    float lamb, float* __restrict__ out)
{
    const int b = blockIdx.x;
    const int t = threadIdx.x;
    const int o = t & 31;
    const int seg = t >> 5;

    float S = 0.f, m[16], q[16];
    #pragma unroll
    for (int k = 0; k < 16; ++k) { m[k] = 0.f; q[k] = 0.f; }
    for (int c = seg; c < NCHK; c += 8) {
        const float* p = part + ((size_t)b*NCHK + c)*PBLK + o*PREC;
        S += p[0];
        #pragma unroll
        for (int k = 0; k < 16; ++k) { m[k] += p[1+k]; q[k] += p[17+k]; }
    }

    __shared__ float sF[8][PBLK];
    {
        float* r = &sF[seg][o*PREC];
        r[0] = S;
        #pragma unroll
        for (int k = 0; k < 16; ++k) { r[1+k] = m[k]; r[17+k] = q[k]; }
    }
    __syncthreads();
    if (t < 32) {
        #pragma unroll
        for (int s = 1; s < 8; ++s) {
            const float* r = &sF[s][o*PREC];
            S += r[0];
            #pragma unroll
            for (int k = 0; k < 16; ++k) { m[k] += r[1+k]; q[k] += r[17+k]; }
        }
        const float invS = 1.f / S;
        float mu[16], var[16], logvarsum = 0.f;
        #pragma unroll
        for (int k = 0; k < 16; ++k) {
            mu[k] = m[k] * invS;
            float vv = q[k]*invS - mu[k]*mu[k];
            vv = fmaxf(vv, 1e-30f);
            var[k] = vv;
            logvarsum += logf(vv);
        }
        const float cost = S * (16.f*beta_u[o] + 0.5f*logvarsum);
        const float x = lamb * (beta_a[o] - cost);
        const float log_a = (x >= 0.f) ? -log1pf(expf(-x)) : (x - log1pf(expf(x)));
        const float LOG2PI = 1.8378770664093453f;
        const float logeff = 16.f*LOG2PI + logvarsum;

        const int tid = b*32 + o;
        lae_g[tid] = log_a + logeff;
        #pragma unroll
        for (int k = 0; k < 16; ++k) {
            mu_g[(size_t)b*512 + k*32 + o]  = mu[k];
            i2v_g[(size_t)b*512 + k*32 + o] = 0.5f / var[k];
        }
        if (out) {
            out[tid] = 1.f / (1.f + expf(-x));
            #pragma unroll
            for (int k = 0; k < 16; ++k)
                out[BATCH*OUT_UNITS + (size_t)tid*16 + k] = mu[k];
        }
    }
}

extern "C" void kernel_launch(void* const* d_in, const int* in_sizes, int n_in,
                              void* d_out, int out_size, void* d_ws, size_t ws_size,
                              hipStream_t stream)
{
    const float* a_in = (const float*)d_in[0];
    const float* Mm   = (const float*)d_in[1];
    const float* Wg   = (const float*)d_in[2];
    const float* bu   = (const float*)d_in[3];
    const float* ba   = (const float*)d_in[4];
    float* out = (float*)d_out;

    char* ws = (char*)d_ws;
    size_t off = 0;
    float* part  = (float*)(ws + off); off += (size_t)BATCH*NCHK*PBLK*sizeof(float);
    float* mu_g  = (float*)(ws + off); off += (size_t)BATCH*512*sizeof(float);
    float* i2v_g = (float*)(ws + off); off += (size_t)BATCH*512*sizeof(float);
    float* lae_g = (float*)(ws + off); off += (size_t)BATCH*32*sizeof(float);
    float* Wt    = (float*)(ws + off); off += (size_t)IN_UNITS*OUT_UNITS*16*sizeof(float);

    // try the cooperative single-kernel path; fall back on launch rejection
    void* args[] = {
        (void*)&a_in, (void*)&Mm, (void*)&Wg,
        (void*)&part, (void*)&mu_g, (void*)&i2v_g, (void*)&lae_g,
        (void*)&bu, (void*)&ba, (void*)&out
    };
    hipError_t e = hipLaunchCooperativeKernel((const void*)caps_all,
                                              dim3(NBLK), dim3(256),
                                              args, 0, stream);
    if (e == hipSuccess) return;
    (void)hipGetLastError();   // clear sticky error, take fallback path

    w_transpose<<<IN_UNITS*512/256, 256, 0, stream>>>(Wg, Wt);
    dim3 grid(NCHK, BATCH), blk(256);
    const float4* Wt4 = (const float4*)Wt;
    caps_main<0><<<grid, blk, 0, stream>>>(a_in, Mm, Wt4, nullptr, nullptr, nullptr, part);
    caps_fin<<<BATCH, 256, 0, stream>>>(part, bu, ba, mu_g, i2v_g, lae_g, 0.01f, nullptr);
    caps_main<1><<<grid, blk, 0, stream>>>(a_in, Mm, Wt4, mu_g, i2v_g, lae_g, part);
    caps_fin<<<BATCH, 256, 0, stream>>>(part, bu, ba, mu_g, i2v_g, lae_g, 0.012f, nullptr);
    caps_main<1><<<grid, blk, 0, stream>>>(a_in, Mm, Wt4, mu_g, i2v_g, lae_g, part);
    caps_fin<<<BATCH, 256, 0, stream>>>(part, bu, ba, mu_g, i2v_g, lae_g, 0.0144f, out);
}

// Round 6
// 108.191 us; speedup vs baseline: 7.8170x; 7.8170x over previous
//
#include <hip/hip_runtime.h>
#include <math.h>

#define IN_UNITS 1152
#define OUT_UNITS 32
#define BATCH 64
#define NCHK 48            // i-chunks; 48%8==0 -> chunk c on XCD c%8
#define IPB 24             // i's per chunk
#define NG 3               // i-groups per chunk (8 i x 32 o per group)
#define PREC 33            // floats per (chunk,o): S, mu[16], v2[16]
#define PBLK (OUT_UNITS*PREC)   // 1056

// thread layout: t = il*32 + o (o = t&31, il = t>>5); lanes l and l^32 share o.

// ---- iteration 0: stats under R = a/32; also emits transposed W (b==0 blocks)
__global__ __launch_bounds__(256, 4) void caps_s0(
    const float* __restrict__ a_in, const float* __restrict__ Mm,
    const float* __restrict__ Wg, float* __restrict__ Wt,
    float* __restrict__ part)
{
    const int t = threadIdx.x, o = t & 31, il = t >> 5, wv = t >> 6, lane = t & 63;
    const int c = blockIdx.x, b = blockIdx.y, i0 = c*IPB;
    __shared__ float sRed[4][PBLK];

    // W rows (original layout W[i][o][ch]) pinned in registers
    float w[NG][16];
    #pragma unroll
    for (int g = 0; g < NG; ++g) {
        const float4* wp = (const float4*)Wg + ((i0 + g*8 + il)*32 + o)*4;
        *(float4*)&w[g][0]  = wp[0];
        *(float4*)&w[g][4]  = wp[1];
        *(float4*)&w[g][8]  = wp[2];
        *(float4*)&w[g][12] = wp[3];
    }
    if (b == 0) {   // emit Wt[i][y][o][z] for the later iterations (coalesced)
        #pragma unroll
        for (int g = 0; g < NG; ++g) {
            const int i = i0 + g*8 + il;
            float4* dst = (float4*)Wt + (i*4)*32 + o;
            #pragma unroll
            for (int y = 0; y < 4; ++y)
                dst[y*32] = make_float4(w[g][y*4+0], w[g][y*4+1],
                                        w[g][y*4+2], w[g][y*4+3]);
        }
    }

    const float4* mbase = (const float4*)Mm + (b*IN_UNITS + i0 + il)*4;
    const float*  abase = a_in + b*IN_UNITS + i0 + il;

    float pS = 0.f, pmu[16], pv2[16];
    #pragma unroll
    for (int k = 0; k < 16; ++k) { pmu[k] = 0.f; pv2[k] = 0.f; }

    #pragma unroll
    for (int g = 0; g < NG; ++g) {
        float Mr[16];   // 64B row broadcast to 32 lanes via L1
        #pragma unroll
        for (int x = 0; x < 4; ++x) *(float4*)&Mr[x*4] = mbase[g*32 + x];
        const float wgt = abase[g*8] * (1.0f/32.0f);

        float v[16];
        #pragma unroll
        for (int x = 0; x < 4; ++x)
            #pragma unroll
            for (int z = 0; z < 4; ++z) {
                float acc = 0.f;
                #pragma unroll
                for (int y = 0; y < 4; ++y)
                    acc = fmaf(Mr[x*4 + y], w[g][y*4 + z], acc);
                v[x*4 + z] = acc;
            }

        pS += wgt;
        #pragma unroll
        for (int k = 0; k < 16; ++k) {
            pmu[k] = fmaf(wgt, v[k], pmu[k]);
            pv2[k] = fmaf(wgt*v[k], v[k], pv2[k]);
        }
    }

    pS += __shfl_xor(pS, 32);
    #pragma unroll
    for (int k = 0; k < 16; ++k) {
        pmu[k] += __shfl_xor(pmu[k], 32);
        pv2[k] += __shfl_xor(pv2[k], 32);
    }
    __syncthreads();
    if (lane < 32) {
        float* r = &sRed[wv][o*PREC];
        r[0] = pS;
        #pragma unroll
        for (int k = 0; k < 16; ++k) { r[1+k] = pmu[k]; r[17+k] = pv2[k]; }
    }
    __syncthreads();
    float* dst = part + (b*NCHK + c)*PBLK;
    for (int idx = t; idx < PBLK; idx += 256)
        dst[idx] = sRed[0][idx] + sRed[1][idx] + sRed[2][idx] + sRed[3][idx];
}

// ---- iterations 1,2: R-update (softmax over o) + stats; W from transposed Wt
__global__ __launch_bounds__(256, 5) void caps_s1(
    const float* __restrict__ a_in, const float* __restrict__ Mm,
    const float4* __restrict__ Wt4,
    const float* __restrict__ mu_g, const float* __restrict__ i2v_g,
    const float* __restrict__ lae_g,
    float* __restrict__ part)
{
    const int t = threadIdx.x, o = t & 31, il = t >> 5, wv = t >> 6, lane = t & 63;
    const int c = blockIdx.x, b = blockIdx.y, i0 = c*IPB;

    __shared__ float sMu[512];
    __shared__ float sI2[512];
    __shared__ float sLae[32];
    __shared__ float sRed[4][PBLK];

    for (int idx = t; idx < 512; idx += 256) {
        sMu[idx] = mu_g[b*512 + idx];
        sI2[idx] = i2v_g[b*512 + idx];
    }
    if (t < 32) sLae[t] = lae_g[b*32 + t];
    __syncthreads();

    const float4* wbase = Wt4 + (i0 + il)*128 + o;            // + g*1024 + y*32
    const float4* mbase = (const float4*)Mm + (b*IN_UNITS + i0 + il)*4;
    const float*  abase = a_in + b*IN_UNITS + i0 + il;

    float pS = 0.f, pmu[16], pv2[16];
    #pragma unroll
    for (int k = 0; k < 16; ++k) { pmu[k] = 0.f; pv2[k] = 0.f; }

    #pragma unroll
    for (int g = 0; g < NG; ++g) {
        float w[16];
        #pragma unroll
        for (int y = 0; y < 4; ++y) *(float4*)&w[y*4] = wbase[g*1024 + y*32];
        float Mr[16];
        #pragma unroll
        for (int x = 0; x < 4; ++x) *(float4*)&Mr[x*4] = mbase[g*32 + x];
        const float a_val = abase[g*8];

        float v[16];
        #pragma unroll
        for (int x = 0; x < 4; ++x)
            #pragma unroll
            for (int z = 0; z < 4; ++z) {
                float acc = 0.f;
                #pragma unroll
                for (int y = 0; y < 4; ++y)
                    acc = fmaf(Mr[x*4 + y], w[y*4 + z], acc);
                v[x*4 + z] = acc;
            }

        float ex0 = 0.f, ex1 = 0.f;
        #pragma unroll
        for (int k = 0; k < 16; k += 2) {
            float d0 = v[k]   - sMu[k*32 + o];
            float d1 = v[k+1] - sMu[(k+1)*32 + o];
            ex0 = fmaf(d0*d0, sI2[k*32 + o], ex0);
            ex1 = fmaf(d1*d1, sI2[(k+1)*32 + o], ex1);
        }
        float logit = sLae[o] - (ex0 + ex1);     // log a + log eff + exponent
        float mx = logit;
        #pragma unroll
        for (int m = 16; m >= 1; m >>= 1) mx = fmaxf(mx, __shfl_xor(mx, m));
        float e = __expf(logit - mx);
        float s = e;
        #pragma unroll
        for (int m = 16; m >= 1; m >>= 1) s += __shfl_xor(s, m);
        const float wgt = (e / s) * a_val;       // R over o, * input_a

        pS += wgt;
        #pragma unroll
        for (int k = 0; k < 16; ++k) {
            pmu[k] = fmaf(wgt, v[k], pmu[k]);
            pv2[k] = fmaf(wgt*v[k], v[k], pv2[k]);
        }
    }

    pS += __shfl_xor(pS, 32);
    #pragma unroll
    for (int k = 0; k < 16; ++k) {
        pmu[k] += __shfl_xor(pmu[k], 32);
        pv2[k] += __shfl_xor(pv2[k], 32);
    }
    __syncthreads();
    if (lane < 32) {
        float* r = &sRed[wv][o*PREC];
        r[0] = pS;
        #pragma unroll
        for (int k = 0; k < 16; ++k) { r[1+k] = pmu[k]; r[17+k] = pv2[k]; }
    }
    __syncthreads();
    float* dst = part + (b*NCHK + c)*PBLK;
    for (int idx = t; idx < PBLK; idx += 256)
        dst[idx] = sRed[0][idx] + sRed[1][idx] + sRed[2][idx] + sRed[3][idx];
}

// ---- finalize: one block per b reduces its 48 chunk-partials
__global__ __launch_bounds__(256) void caps_fin(
    const float* __restrict__ part,
    const float* __restrict__ beta_u, const float* __restrict__ beta_a,
    float* __restrict__ mu_g, float* __restrict__ i2v_g, float* __restrict__ lae_g,
    float lamb, float* __restrict__ out)
{
    const int b = blockIdx.x;
    const int t = threadIdx.x;
    const int o = t & 31;
    const int seg = t >> 5;

    float S = 0.f, m[16], q[16];
    #pragma unroll
    for (int k = 0; k < 16; ++k) { m[k] = 0.f; q[k] = 0.f; }
    for (int c = seg; c < NCHK; c += 8) {
        const float* p = part + (b*NCHK + c)*PBLK + o*PREC;
        S += p[0];
        #pragma unroll
        for (int k = 0; k < 16; ++k) { m[k] += p[1+k]; q[k] += p[17+k]; }
    }

    __shared__ float sF[8][PBLK];
    {
        float* r = &sF[seg][o*PREC];
        r[0] = S;
        #pragma unroll
        for (int k = 0; k < 16; ++k) { r[1+k] = m[k]; r[17+k] = q[k]; }
    }
    __syncthreads();
    if (t < 32) {
        #pragma unroll
        for (int s = 1; s < 8; ++s) {
            const float* r = &sF[s][o*PREC];
            S += r[0];
            #pragma unroll
            for (int k = 0; k < 16; ++k) { m[k] += r[1+k]; q[k] += r[17+k]; }
        }
        const float invS = 1.f / S;
        float mu[16], var[16], logvarsum = 0.f;
        #pragma unroll
        for (int k = 0; k < 16; ++k) {
            mu[k] = m[k] * invS;
            float vv = q[k]*invS - mu[k]*mu[k];   // E[v^2] - mu^2
            vv = fmaxf(vv, 1e-30f);
            var[k] = vv;
            logvarsum += logf(vv);
        }
        const float cost = S * (16.f*beta_u[o] + 0.5f*logvarsum);
        const float x = lamb * (beta_a[o] - cost);
        const float log_a = (x >= 0.f) ? -log1pf(expf(-x)) : (x - log1pf(expf(x)));
        const float LOG2PI = 1.8378770664093453f;
        const float logeff = 16.f*LOG2PI + logvarsum;

        const int tid = b*32 + o;
        lae_g[tid] = log_a + logeff;
        #pragma unroll
        for (int k = 0; k < 16; ++k) {
            mu_g[b*512 + k*32 + o]  = mu[k];
            i2v_g[b*512 + k*32 + o] = 0.5f / var[k];
        }
        if (out) {
            out[tid] = 1.f / (1.f + expf(-x));                      // a (64,32)
            #pragma unroll
            for (int k = 0; k < 16; ++k)
                out[BATCH*OUT_UNITS + tid*16 + k] = mu[k];          // mu (64,32,16)
        }
    }
}

extern "C" void kernel_launch(void* const* d_in, const int* in_sizes, int n_in,
                              void* d_out, int out_size, void* d_ws, size_t ws_size,
                              hipStream_t stream)
{
    const float* a_in = (const float*)d_in[0];
    const float* Mm   = (const float*)d_in[1];
    const float* Wg   = (const float*)d_in[2];
    const float* bu   = (const float*)d_in[3];
    const float* ba   = (const float*)d_in[4];
    float* out = (float*)d_out;

    char* ws = (char*)d_ws;
    size_t off = 0;
    float* part  = (float*)(ws + off); off += (size_t)BATCH*NCHK*PBLK*sizeof(float);
    float* mu_g  = (float*)(ws + off); off += (size_t)BATCH*512*sizeof(float);
    float* i2v_g = (float*)(ws + off); off += (size_t)BATCH*512*sizeof(float);
    float* lae_g = (float*)(ws + off); off += (size_t)BATCH*32*sizeof(float);
    float* Wt    = (float*)(ws + off); off += (size_t)IN_UNITS*OUT_UNITS*16*sizeof(float);

    dim3 grid(NCHK, BATCH), blk(256);
    const float4* Wt4 = (const float4*)Wt;

    caps_s0<<<grid, blk, 0, stream>>>(a_in, Mm, Wg, Wt, part);
    caps_fin<<<BATCH, 256, 0, stream>>>(part, bu, ba, mu_g, i2v_g, lae_g, 0.01f, nullptr);
    caps_s1<<<grid, blk, 0, stream>>>(a_in, Mm, Wt4, mu_g, i2v_g, lae_g, part);
    caps_fin<<<BATCH, 256, 0, stream>>>(part, bu, ba, mu_g, i2v_g, lae_g, 0.012f, nullptr);
    caps_s1<<<grid, blk, 0, stream>>>(a_in, Mm, Wt4, mu_g, i2v_g, lae_g, part);
    caps_fin<<<BATCH, 256, 0, stream>>>(part, bu, ba, mu_g, i2v_g, lae_g, 0.0144f, out);
}

// Round 7
// 79.158 us; speedup vs baseline: 10.6841x; 1.3668x over previous
//
#include <hip/hip_runtime.h>
#include <math.h>

#define IN_UNITS 1152
#define OUT_UNITS 32
#define BATCH 64
#define NCHK 24            // i-chunks; 24%8==0 -> chunk c on XCD c%8
#define IPB 48             // i's per chunk
#define NG 6               // i-groups per chunk (8 i x 32 o per group)
#define PREC 33            // values per (chunk,o): S, mu[16], v2[16]
#define PBLK (PREC*OUT_UNITS)   // 1056 floats, layout [j][o] (o-minor)

// W[i][o][ch] -> Wt[i][y][o][z] (ch=y*4+z). Output-coalesced: consecutive gid
// = consecutive Wt address; reads are 16B-granule gathers (one-time, 2.4 MB).
__global__ __launch_bounds__(256) void w_transpose(
    const float* __restrict__ W, float* __restrict__ Wt)
{
    const int gid = blockIdx.x*256 + threadIdx.x;   // 1152*512
    const int i = gid >> 9, rem = gid & 511;
    const int y = rem >> 7, o = (rem >> 2) & 31, z = rem & 3;
    Wt[gid] = W[i*512 + o*16 + y*4 + z];
}

// thread layout: t = il*32 + o (o=t&31, il=t>>5); lanes l,l^32 share o.
// MODE 0: stats under R = a/32.  MODE 1: R-update (softmax over o) + stats.
template<int MODE>
__global__ __launch_bounds__(256, 4) void caps_main(
    const float* __restrict__ a_in, const float* __restrict__ Mm,
    const float4* __restrict__ Wt4,
    const float* __restrict__ mu_g, const float* __restrict__ i2v_g,
    const float* __restrict__ lae_g,
    float* __restrict__ part)
{
    const int t = threadIdx.x, o = t & 31, il = t >> 5, wv = t >> 6, lane = t & 63;
    const int c = blockIdx.x, b = blockIdx.y, i0 = c*IPB;

    __shared__ float sRed[4][PBLK];   // 16.9 KB

    // per-thread routing state for this o, in registers (no LDS, no barrier)
    float rmu[16], ri2[16], lae = 0.f;
    if (MODE) {
        #pragma unroll
        for (int k = 0; k < 16; ++k) {
            rmu[k] = mu_g[b*512 + k*32 + o];    // coalesced across o
            ri2[k] = i2v_g[b*512 + k*32 + o];
        }
        lae = lae_g[b*32 + o];                  // log a + log eff
    }

    const float4* wbase = Wt4 + (i0 + il)*128 + o;              // +g*1024 +y*32
    const float4* mbase = (const float4*)Mm + (b*IN_UNITS + i0 + il)*4;  // +g*32 +x
    const float*  abase = a_in + b*IN_UNITS + i0 + il;          // +g*8

    float pS = 0.f, pmu[16], pv2[16];
    #pragma unroll
    for (int k = 0; k < 16; ++k) { pmu[k] = 0.f; pv2[k] = 0.f; }

    #pragma unroll
    for (int g = 0; g < NG; ++g) {
        float w[16];
        #pragma unroll
        for (int y = 0; y < 4; ++y) *(float4*)&w[y*4] = wbase[g*1024 + y*32];
        float Mr[16];   // 64B row broadcast to 32 lanes via L1
        #pragma unroll
        for (int x = 0; x < 4; ++x) *(float4*)&Mr[x*4] = mbase[g*32 + x];
        const float a_val = abase[g*8];

        float v[16];
        #pragma unroll
        for (int x = 0; x < 4; ++x)
            #pragma unroll
            for (int z = 0; z < 4; ++z) {
                float acc = 0.f;
                #pragma unroll
                for (int y = 0; y < 4; ++y)
                    acc = fmaf(Mr[x*4 + y], w[y*4 + z], acc);
                v[x*4 + z] = acc;
            }

        float wgt;
        if (MODE == 0) {
            wgt = a_val * (1.0f/32.0f);          // R0 = 1/32
        } else {
            // direct (no max-sub), mirrors reference: p = eff*exp(-ex), numer=a*p
            float ex0 = 0.f, ex1 = 0.f;
            #pragma unroll
            for (int k = 0; k < 16; k += 2) {
                float d0 = v[k]   - rmu[k];
                float d1 = v[k+1] - rmu[k+1];
                ex0 = fmaf(d0*d0, ri2[k],   ex0);
                ex1 = fmaf(d1*d1, ri2[k+1], ex1);
            }
            float e = __expf(lae - (ex0 + ex1)); // a*eff*exp(exponent)
            float s = e;
            #pragma unroll
            for (int m = 16; m >= 1; m >>= 1) s += __shfl_xor(s, m);
            wgt = (e / s) * a_val;               // R over o, * input_a
        }

        pS += wgt;
        #pragma unroll
        for (int k = 0; k < 16; ++k) {
            pmu[k] = fmaf(wgt, v[k], pmu[k]);
            pv2[k] = fmaf(wgt*v[k], v[k], pv2[k]);
        }
    }

    // lanes l <-> l^32 share o
    pS += __shfl_xor(pS, 32);
    #pragma unroll
    for (int k = 0; k < 16; ++k) {
        pmu[k] += __shfl_xor(pmu[k], 32);
        pv2[k] += __shfl_xor(pv2[k], 32);
    }
    if (lane < 32) {   // [j][o] layout: conflict-free, coalesced downstream
        float* r = &sRed[wv][0];
        r[o] = pS;
        #pragma unroll
        for (int k = 0; k < 16; ++k) {
            r[(1+k)*32 + o]  = pmu[k];
            r[(17+k)*32 + o] = pv2[k];
        }
    }
    __syncthreads();
    float* dst = part + (b*NCHK + c)*PBLK;
    for (int idx = t; idx < PBLK; idx += 256)
        dst[idx] = sRed[0][idx] + sRed[1][idx] + sRed[2][idx] + sRed[3][idx];
}

// finalize: one block per b reduces its 24 chunk-partials (seg handles 3)
__global__ __launch_bounds__(256) void caps_fin(
    const float* __restrict__ part,
    const float* __restrict__ beta_u, const float* __restrict__ beta_a,
    float* __restrict__ mu_g, float* __restrict__ i2v_g, float* __restrict__ lae_g,
    float lamb, float* __restrict__ out)
{
    const int b = blockIdx.x;
    const int t = threadIdx.x;
    const int o = t & 31;
    const int seg = t >> 5;

    float S = 0.f, m[16], q[16];
    #pragma unroll
    for (int k = 0; k < 16; ++k) { m[k] = 0.f; q[k] = 0.f; }
    #pragma unroll
    for (int cc = 0; cc < 3; ++cc) {
        const float* p = part + (b*NCHK + seg + cc*8)*PBLK;
        S += p[o];
        #pragma unroll
        for (int k = 0; k < 16; ++k) {
            m[k] += p[(1+k)*32 + o];
            q[k] += p[(17+k)*32 + o];
        }
    }

    __shared__ float sF[8][PBLK];
    {
        float* r = &sF[seg][0];
        r[o] = S;
        #pragma unroll
        for (int k = 0; k < 16; ++k) { r[(1+k)*32+o] = m[k]; r[(17+k)*32+o] = q[k]; }
    }
    __syncthreads();
    if (t < 32) {
        #pragma unroll
        for (int s = 1; s < 8; ++s) {
            const float* r = &sF[s][0];
            S += r[o];
            #pragma unroll
            for (int k = 0; k < 16; ++k) { m[k] += r[(1+k)*32+o]; q[k] += r[(17+k)*32+o]; }
        }
        const float invS = 1.f / S;
        float mu[16], var[16], logvarsum = 0.f;
        #pragma unroll
        for (int k = 0; k < 16; ++k) {
            mu[k] = m[k] * invS;
            float vv = q[k]*invS - mu[k]*mu[k];   // E[v^2] - mu^2
            vv = fmaxf(vv, 1e-30f);
            var[k] = vv;
            logvarsum += logf(vv);
        }
        const float cost = S * (16.f*beta_u[o] + 0.5f*logvarsum);
        const float x = lamb * (beta_a[o] - cost);
        const float log_a = (x >= 0.f) ? -log1pf(expf(-x)) : (x - log1pf(expf(x)));
        const float LOG2PI = 1.8378770664093453f;
        const float logeff = 16.f*LOG2PI + logvarsum;

        const int tid = b*32 + o;
        lae_g[tid] = log_a + logeff;
        #pragma unroll
        for (int k = 0; k < 16; ++k) {
            mu_g[b*512 + k*32 + o]  = mu[k];
            i2v_g[b*512 + k*32 + o] = 0.5f / var[k];
        }
        if (out) {
            out[tid] = 1.f / (1.f + expf(-x));                      // a (64,32)
            #pragma unroll
            for (int k = 0; k < 16; ++k)
                out[BATCH*OUT_UNITS + tid*16 + k] = mu[k];          // mu (64,32,16)
        }
    }
}

extern "C" void kernel_launch(void* const* d_in, const int* in_sizes, int n_in,
                              void* d_out, int out_size, void* d_ws, size_t ws_size,
                              hipStream_t stream)
{
    const float* a_in = (const float*)d_in[0];
    const float* Mm   = (const float*)d_in[1];
    const float* Wg   = (const float*)d_in[2];
    const float* bu   = (const float*)d_in[3];
    const float* ba   = (const float*)d_in[4];
    float* out = (float*)d_out;

    char* ws = (char*)d_ws;
    size_t off = 0;
    float* part  = (float*)(ws + off); off += (size_t)BATCH*NCHK*PBLK*sizeof(float);
    float* mu_g  = (float*)(ws + off); off += (size_t)BATCH*512*sizeof(float);
    float* i2v_g = (float*)(ws + off); off += (size_t)BATCH*512*sizeof(float);
    float* lae_g = (float*)(ws + off); off += (size_t)BATCH*32*sizeof(float);
    float* Wt    = (float*)(ws + off); off += (size_t)IN_UNITS*OUT_UNITS*16*sizeof(float);

    dim3 grid(NCHK, BATCH), blk(256);
    const float4* Wt4 = (const float4*)Wt;

    w_transpose<<<IN_UNITS*512/256, 256, 0, stream>>>(Wg, Wt);
    caps_main<0><<<grid, blk, 0, stream>>>(a_in, Mm, Wt4, nullptr, nullptr, nullptr, part);
    caps_fin<<<BATCH, 256, 0, stream>>>(part, bu, ba, mu_g, i2v_g, lae_g, 0.01f, nullptr);
    caps_main<1><<<grid, blk, 0, stream>>>(a_in, Mm, Wt4, mu_g, i2v_g, lae_g, part);
    caps_fin<<<BATCH, 256, 0, stream>>>(part, bu, ba, mu_g, i2v_g, lae_g, 0.012f, nullptr);
    caps_main<1><<<grid, blk, 0, stream>>>(a_in, Mm, Wt4, mu_g, i2v_g, lae_g, part);
    caps_fin<<<BATCH, 256, 0, stream>>>(part, bu, ba, mu_g, i2v_g, lae_g, 0.0144f, out);
}